// Round 2
// baseline (1911.290 us; speedup 1.0000x reference)
//
#include <hip/hip_runtime.h>
#include <math.h>

// ---------------------------------------------------------------------------
// Masked MHA, fp32 correctness-first baseline.
//   B=4 S=2048 D=1024 H=16 HD=64
//   out = mask_q * ( Attn( mask*x ) @ Wo^T + bo )
// Pipeline:
//   1. proj_gemm<mask_in, split_heads>  x3  : X -> Q,K,V  [B,H,S,HD]
//   2. attn_fp32 (flash, online softmax, -1e9 key masking)  -> ctx [B,S,D]
//   3. proj_gemm<mask_out>                  : ctx -> out   [B,S,D]
// Workspace: Q,K,V,ctx = 4 * 33.5 MB = 134 MB in d_ws.
// ---------------------------------------------------------------------------

constexpr int B_ = 4, S_ = 2048, D_ = 1024, H_ = 16, HD_ = 64;
constexpr float SCALE_ = 0.125f;      // 1/sqrt(64)
constexpr float BIG_NEG_ = -1e9f;

// C[m,n] = sum_k X[m,k] * W[n,k] + bias[n]    (torch Linear: x @ W^T + b)
// M=8192, N=1024, K=1024. BM=BN=128, BK=16, 256 thr, 8x8 per thread.
template<bool MASK_IN, bool SPLIT_HEADS, bool MASK_OUT>
__global__ __launch_bounds__(256)
void proj_gemm(const float* __restrict__ X, const float* __restrict__ W,
               const float* __restrict__ bias, const int* __restrict__ mask,
               float* __restrict__ C)
{
    // k-major LDS tiles; stride 132 floats: writes 2-way, reads conflict-free
    __shared__ float Xs[16][132];
    __shared__ float Ws[16][132];

    const int tid = threadIdx.x;
    const int tx = tid & 15, ty = tid >> 4;
    const int m0 = blockIdx.x * 128, n0 = blockIdx.y * 128;

    const int lrow = tid >> 2;          // 0..63
    const int lcol = (tid & 3) << 2;    // 0,4,8,12

    float acc[8][8] = {};

    for (int k0 = 0; k0 < D_; k0 += 16) {
        #pragma unroll
        for (int half = 0; half < 2; ++half) {
            const int row = lrow + half * 64;
            const int gm = m0 + row;
            float4 xv = *reinterpret_cast<const float4*>(&X[(size_t)gm * D_ + k0 + lcol]);
            if (MASK_IN) {
                const float mf = (float)mask[gm];
                xv.x *= mf; xv.y *= mf; xv.z *= mf; xv.w *= mf;
            }
            Xs[lcol + 0][row] = xv.x;
            Xs[lcol + 1][row] = xv.y;
            Xs[lcol + 2][row] = xv.z;
            Xs[lcol + 3][row] = xv.w;
            const int gn = n0 + row;
            const float4 wv = *reinterpret_cast<const float4*>(&W[(size_t)gn * D_ + k0 + lcol]);
            Ws[lcol + 0][row] = wv.x;
            Ws[lcol + 1][row] = wv.y;
            Ws[lcol + 2][row] = wv.z;
            Ws[lcol + 3][row] = wv.w;
        }
        __syncthreads();
        #pragma unroll
        for (int kk = 0; kk < 16; ++kk) {
            float x8[8], w8[8];
            *reinterpret_cast<float4*>(&x8[0]) = *reinterpret_cast<const float4*>(&Xs[kk][ty * 8]);
            *reinterpret_cast<float4*>(&x8[4]) = *reinterpret_cast<const float4*>(&Xs[kk][ty * 8 + 4]);
            *reinterpret_cast<float4*>(&w8[0]) = *reinterpret_cast<const float4*>(&Ws[kk][tx * 8]);
            *reinterpret_cast<float4*>(&w8[4]) = *reinterpret_cast<const float4*>(&Ws[kk][tx * 8 + 4]);
            #pragma unroll
            for (int i = 0; i < 8; ++i)
                #pragma unroll
                for (int j = 0; j < 8; ++j)
                    acc[i][j] = fmaf(x8[i], w8[j], acc[i][j]);
        }
        __syncthreads();
    }

    #pragma unroll
    for (int i = 0; i < 8; ++i) {
        const int gm = m0 + ty * 8 + i;
        float mf = 1.0f;
        if (MASK_OUT) mf = (float)mask[gm];
        #pragma unroll
        for (int jv = 0; jv < 2; ++jv) {
            const int gn = n0 + tx * 8 + jv * 4;
            float4 r;
            r.x = acc[i][jv * 4 + 0] + bias[gn + 0];
            r.y = acc[i][jv * 4 + 1] + bias[gn + 1];
            r.z = acc[i][jv * 4 + 2] + bias[gn + 2];
            r.w = acc[i][jv * 4 + 3] + bias[gn + 3];
            if (MASK_OUT) { r.x *= mf; r.y *= mf; r.z *= mf; r.w *= mf; }
            if (SPLIT_HEADS) {
                // [B,S,D] logical (m, n=h*64+hd) -> [B,H,S,HD]
                const int b = gm >> 11, s = gm & (S_ - 1);
                const int h = gn >> 6, hd = gn & 63;
                *reinterpret_cast<float4*>(
                    &C[(((size_t)(b * H_ + h)) * S_ + s) * HD_ + hd]) = r;
            } else {
                *reinterpret_cast<float4*>(&C[(size_t)gm * D_ + gn]) = r;
            }
        }
    }
}

// Flash attention, fp32. One block = (b, h, 64-row q tile). 256 thr = 16x16.
// scores GEMM 64x64x64 (4x4/thread) -> online softmax (shfl over 16 tx lanes)
// -> P staged transposed (wave-private columns) -> PV GEMM 64x64x64.
__global__ __launch_bounds__(256)
void attn_fp32(const float* __restrict__ Q, const float* __restrict__ K,
               const float* __restrict__ V, const int* __restrict__ mask,
               float* __restrict__ ctx)
{
    __shared__ float Qt[HD_][68];   // [d][q], pad 68: conflict-free b128 reads
    __shared__ float Kt[HD_][68];   // [d][k]
    __shared__ float Vs[64][68];    // [k][hd]
    __shared__ float Pt[64][68];    // [k][q]

    const int tid = threadIdx.x;
    const int tx = tid & 15, ty = tid >> 4;
    const int q0 = blockIdx.x * 64;
    const int h  = blockIdx.y;
    const int b  = blockIdx.z;

    const size_t headoff = ((size_t)(b * H_ + h)) * S_ * HD_;
    const int maskbase = b * S_;

    {   // load Q tile, pre-scaled, transposed [d][q]
        const int r = tid >> 2;
        const int cbase = (tid & 3) << 2;
        #pragma unroll
        for (int cc = 0; cc < 4; ++cc) {
            const int c = cbase + cc * 16;
            const float4 v = *reinterpret_cast<const float4*>(
                &Q[headoff + (size_t)(q0 + r) * HD_ + c]);
            Qt[c + 0][r] = v.x * SCALE_;
            Qt[c + 1][r] = v.y * SCALE_;
            Qt[c + 2][r] = v.z * SCALE_;
            Qt[c + 3][r] = v.w * SCALE_;
        }
    }

    float m_run[4], l_run[4], o[4][4];
    #pragma unroll
    for (int i = 0; i < 4; ++i) {
        m_run[i] = -INFINITY; l_run[i] = 0.f;
        #pragma unroll
        for (int j = 0; j < 4; ++j) o[i][j] = 0.f;
    }

    for (int k0 = 0; k0 < S_; k0 += 64) {
        __syncthreads();   // protect Kt/Vs against previous iteration readers
        {
            const int r = tid >> 2;
            const int cbase = (tid & 3) << 2;
            #pragma unroll
            for (int cc = 0; cc < 4; ++cc) {
                const int c = cbase + cc * 16;
                const float4 kv = *reinterpret_cast<const float4*>(
                    &K[headoff + (size_t)(k0 + r) * HD_ + c]);
                Kt[c + 0][r] = kv.x;
                Kt[c + 1][r] = kv.y;
                Kt[c + 2][r] = kv.z;
                Kt[c + 3][r] = kv.w;
                const float4 vv = *reinterpret_cast<const float4*>(
                    &V[headoff + (size_t)(k0 + r) * HD_ + c]);
                *reinterpret_cast<float4*>(&Vs[r][c]) = vv;
            }
        }
        __syncthreads();

        const int4 km = *reinterpret_cast<const int4*>(&mask[maskbase + k0 + tx * 4]);

        // scores: S[q=ty*4+i][k=tx*4+j], Q pre-scaled by 1/sqrt(hd)
        float sc[4][4] = {};
        #pragma unroll 8
        for (int d = 0; d < HD_; ++d) {
            float a4[4], b4[4];
            *reinterpret_cast<float4*>(a4) = *reinterpret_cast<const float4*>(&Qt[d][ty * 4]);
            *reinterpret_cast<float4*>(b4) = *reinterpret_cast<const float4*>(&Kt[d][tx * 4]);
            #pragma unroll
            for (int i = 0; i < 4; ++i)
                #pragma unroll
                for (int j = 0; j < 4; ++j)
                    sc[i][j] = fmaf(a4[i], b4[j], sc[i][j]);
        }
        #pragma unroll
        for (int i = 0; i < 4; ++i) {
            sc[i][0] = (km.x != 0) ? sc[i][0] : BIG_NEG_;
            sc[i][1] = (km.y != 0) ? sc[i][1] : BIG_NEG_;
            sc[i][2] = (km.z != 0) ? sc[i][2] : BIG_NEG_;
            sc[i][3] = (km.w != 0) ? sc[i][3] : BIG_NEG_;
        }

        // online softmax; row owned by 16 tx lanes (shfl_xor 1,2,4,8)
        #pragma unroll
        for (int i = 0; i < 4; ++i) {
            float tmax = fmaxf(fmaxf(sc[i][0], sc[i][1]), fmaxf(sc[i][2], sc[i][3]));
            tmax = fmaxf(tmax, __shfl_xor(tmax, 1));
            tmax = fmaxf(tmax, __shfl_xor(tmax, 2));
            tmax = fmaxf(tmax, __shfl_xor(tmax, 4));
            tmax = fmaxf(tmax, __shfl_xor(tmax, 8));
            const float mn = fmaxf(m_run[i], tmax);
            const float corr = __expf(m_run[i] - mn);   // exp(-inf)=0 first tile
            m_run[i] = mn;
            float rs = 0.f;
            #pragma unroll
            for (int j = 0; j < 4; ++j) {
                sc[i][j] = __expf(sc[i][j] - mn);       // masked: exp(~-1e9)=0
                rs += sc[i][j];
            }
            rs += __shfl_xor(rs, 1);
            rs += __shfl_xor(rs, 2);
            rs += __shfl_xor(rs, 4);
            rs += __shfl_xor(rs, 8);
            l_run[i] = l_run[i] * corr + rs;
            #pragma unroll
            for (int j = 0; j < 4; ++j) o[i][j] *= corr;
        }

        // stage P transposed [k][q]; columns are wave-private -> no barrier
        #pragma unroll
        for (int i = 0; i < 4; ++i)
            #pragma unroll
            for (int j = 0; j < 4; ++j)
                Pt[tx * 4 + j][ty * 4 + i] = sc[i][j];

        // PV: o[q=ty*4+i][hd=tx*4+j] += P[q][kk] * V[kk][hd]
        #pragma unroll 8
        for (int kk = 0; kk < 64; ++kk) {
            float p4[4], v4[4];
            *reinterpret_cast<float4*>(p4) = *reinterpret_cast<const float4*>(&Pt[kk][ty * 4]);
            *reinterpret_cast<float4*>(v4) = *reinterpret_cast<const float4*>(&Vs[kk][tx * 4]);
            #pragma unroll
            for (int i = 0; i < 4; ++i)
                #pragma unroll
                for (int j = 0; j < 4; ++j)
                    o[i][j] = fmaf(p4[i], v4[j], o[i][j]);
        }
    }

    // epilogue: ctx[b, s, h*64+hd] = o / l   (store [B,S,D] for out-proj)
    #pragma unroll
    for (int i = 0; i < 4; ++i) {
        const float inv = 1.0f / l_run[i];
        const int s = q0 + ty * 4 + i;
        float4 r;
        r.x = o[i][0] * inv; r.y = o[i][1] * inv;
        r.z = o[i][2] * inv; r.w = o[i][3] * inv;
        *reinterpret_cast<float4*>(
            &ctx[((size_t)(b * S_) + s) * D_ + h * HD_ + tx * 4]) = r;
    }
}

extern "C" void kernel_launch(void* const* d_in, const int* in_sizes, int n_in,
                              void* d_out, int out_size, void* d_ws, size_t ws_size,
                              hipStream_t stream) {
    const float* hidden = (const float*)d_in[0];
    const int*   mask   = (const int*)d_in[1];
    const float* Wq = (const float*)d_in[2];
    const float* bq = (const float*)d_in[3];
    const float* Wk = (const float*)d_in[4];
    const float* bk = (const float*)d_in[5];
    const float* Wv = (const float*)d_in[6];
    const float* bv = (const float*)d_in[7];
    const float* Wo = (const float*)d_in[8];
    const float* bo = (const float*)d_in[9];
    float* out = (float*)d_out;

    float* ws = (float*)d_ws;
    const size_t T = (size_t)B_ * H_ * S_ * HD_;   // 8388608
    float* Qb = ws;
    float* Kb = ws + T;
    float* Vb = ws + 2 * T;
    float* Cb = ws + 3 * T;

    const dim3 gg(64, 8), bb(256);
    proj_gemm<true,  true,  false><<<gg, bb, 0, stream>>>(hidden, Wq, bq, mask, Qb);
    proj_gemm<true,  true,  false><<<gg, bb, 0, stream>>>(hidden, Wk, bk, mask, Kb);
    proj_gemm<true,  true,  false><<<gg, bb, 0, stream>>>(hidden, Wv, bv, mask, Vb);
    attn_fp32<<<dim3(S_ / 64, H_, B_), bb, 0, stream>>>(Qb, Kb, Vb, mask, Cb);
    proj_gemm<false, false, true ><<<gg, bb, 0, stream>>>(Cb, Wo, bo, mask, out);
}

// Round 4
// 487.296 us; speedup vs baseline: 3.9222x; 3.9222x over previous
//
#include <hip/hip_runtime.h>
#include <math.h>

// ---------------------------------------------------------------------------
// Masked MHA, bf16-MFMA pipeline.  B=4 S=2048 D=1024 H=16 HD=64
//  1. gemm_bf16<Q/K/V>: X(f32,masked,staged->bf16) @ W^T + b -> bf16 [B,H,S,HD]
//     (Q pre-scaled by 1/sqrt(HD))
//  2. transpose_v: V [B,H,S,HD] -> VT [B,H,HD,S]   (bf16)
//  3. attn_bf16: flash, MFMA QK^T + PV, online softmax fp32, -1e9 key mask
//     -> ctx bf16 [B,S,D]
//  4. gemm_bf16<OUT>: ctx @ Wo^T + bo, query-mask -> f32 out
// MFMA fragment layouts (gfx950, guide-verified):
//   A/B: lane l supplies row/col (l&15), k = (l>>4)*8 + j  (8 contig bf16)
//   C/D: col = l&15, row = (l>>4)*4 + reg
// ---------------------------------------------------------------------------

typedef __attribute__((ext_vector_type(4))) float f32x4;
typedef __attribute__((ext_vector_type(8))) short s16x8;

#define MFMA16(a, b, c) __builtin_amdgcn_mfma_f32_16x16x32_bf16((a), (b), (c), 0, 0, 0)

constexpr int B_ = 4, S_ = 2048, D_ = 1024, H_ = 16, HD_ = 64;
constexpr float SCALE_ = 0.125f;
constexpr float BIG_NEG_ = -1e9f;

__device__ __forceinline__ ushort f2b(float x) {   // f32 -> bf16 bits, RNE
    unsigned u = __float_as_uint(x);
    return (ushort)((u + 0x7FFFu + ((u >> 16) & 1u)) >> 16);
}

// ---------------------------------------------------------------------------
// GEMM: C[m,n] = sum_k X[m,k]*W[n,k] + bias[n].  M=8192,N=1024,K=1024.
// 128x128 tile, 4 waves (2x2 of 64x64), BK=64, reg-staged f32->bf16 LDS.
// EPI: 0=Q(bf16,scale,split) 1=K 2=V (bf16,split) 3=OUT(f32,row-mask)
// ---------------------------------------------------------------------------
template<int EPI>
__global__ __launch_bounds__(256)
void gemm_bf16(const float* __restrict__ Xf, const ushort* __restrict__ Xb,
               const float* __restrict__ W, const float* __restrict__ bias,
               const int* __restrict__ mask, float* __restrict__ Cf,
               ushort* __restrict__ Cb)
{
    __shared__ ushort Xs[128 * 64];
    __shared__ ushort Ws[128 * 64];

    const int t = threadIdx.x;
    const int lane = t & 63, w = t >> 6;
    const int wr = w >> 1, wc = w & 1;
    const int lrow = lane & 15, lk = lane >> 4;
    const int m0 = blockIdx.x * 128, n0 = blockIdx.y * 128;

    f32x4 acc[4][4];
    #pragma unroll
    for (int i = 0; i < 4; ++i)
        #pragma unroll
        for (int j = 0; j < 4; ++j) acc[i][j] = (f32x4)0.f;

    for (int k0 = 0; k0 < D_; k0 += 64) {
        __syncthreads();
        #pragma unroll
        for (int p = 0; p < 4; ++p) {
            const int c = t + p * 256;          // 1024 16B-chunks per operand
            const int row = c >> 3, slot = c & 7;
            // X tile
            if (EPI == 3) {
                *(s16x8*)(Xs + row * 64 + slot * 8) =
                    *(const s16x8*)(Xb + (size_t)(m0 + row) * 1024 + k0 + slot * 8);
            } else {
                const float* xs = Xf + (size_t)(m0 + row) * 1024 + k0 + slot * 8;
                const float4 a = *(const float4*)xs;
                const float4 b = *(const float4*)(xs + 4);
                const float mf = (float)mask[m0 + row];
                s16x8 v;
                v[0] = (short)f2b(a.x * mf); v[1] = (short)f2b(a.y * mf);
                v[2] = (short)f2b(a.z * mf); v[3] = (short)f2b(a.w * mf);
                v[4] = (short)f2b(b.x * mf); v[5] = (short)f2b(b.y * mf);
                v[6] = (short)f2b(b.z * mf); v[7] = (short)f2b(b.w * mf);
                *(s16x8*)(Xs + row * 64 + slot * 8) = v;
            }
            // W tile
            {
                const float* wsrc = W + (size_t)(n0 + row) * 1024 + k0 + slot * 8;
                const float4 a = *(const float4*)wsrc;
                const float4 b = *(const float4*)(wsrc + 4);
                s16x8 v;
                v[0] = (short)f2b(a.x); v[1] = (short)f2b(a.y);
                v[2] = (short)f2b(a.z); v[3] = (short)f2b(a.w);
                v[4] = (short)f2b(b.x); v[5] = (short)f2b(b.y);
                v[6] = (short)f2b(b.z); v[7] = (short)f2b(b.w);
                *(s16x8*)(Ws + row * 64 + slot * 8) = v;
            }
        }
        __syncthreads();

        #pragma unroll
        for (int kk = 0; kk < 2; ++kk) {
            s16x8 af[4], bf[4];
            #pragma unroll
            for (int i = 0; i < 4; ++i)
                af[i] = *(const s16x8*)(Xs + (wr * 64 + i * 16 + lrow) * 64 + kk * 32 + lk * 8);
            #pragma unroll
            for (int j = 0; j < 4; ++j)
                bf[j] = *(const s16x8*)(Ws + (wc * 64 + j * 16 + lrow) * 64 + kk * 32 + lk * 8);
            #pragma unroll
            for (int i = 0; i < 4; ++i)
                #pragma unroll
                for (int j = 0; j < 4; ++j)
                    acc[i][j] = MFMA16(af[i], bf[j], acc[i][j]);
        }
    }

    #pragma unroll
    for (int i = 0; i < 4; ++i) {
        #pragma unroll
        for (int j = 0; j < 4; ++j) {
            const int gn = n0 + wc * 64 + j * 16 + lrow;
            const float bb = bias[gn];
            #pragma unroll
            for (int r = 0; r < 4; ++r) {
                const int gm = m0 + wr * 64 + i * 16 + lk * 4 + r;
                float v = acc[i][j][r] + bb;
                if (EPI == 0) v *= SCALE_;
                if (EPI <= 2) {
                    const int b_ = gm >> 11, s_ = gm & (S_ - 1);
                    const int h_ = gn >> 6, hd_ = gn & 63;
                    Cb[(((size_t)(b_ * H_ + h_)) * S_ + s_) * HD_ + hd_] = f2b(v);
                } else {
                    v *= (float)mask[gm];
                    Cf[(size_t)gm * 1024 + gn] = v;
                }
            }
        }
    }
}

// ---------------------------------------------------------------------------
// V [B,H,S,HD] bf16 -> VT [B,H,HD,S] bf16.  One block = (s-tile 64, h, b).
// ---------------------------------------------------------------------------
__global__ __launch_bounds__(256)
void transpose_v(const ushort* __restrict__ V, ushort* __restrict__ VT)
{
    __shared__ ushort L[64][72];
    const int t = threadIdx.x;
    const int s0 = blockIdx.x * 64;
    const size_t base = ((size_t)(blockIdx.z * H_ + blockIdx.y)) * S_ * HD_;
    const int r = t >> 2, cb = (t & 3) * 16;

    *(s16x8*)&L[r][cb]     = *(const s16x8*)(V + base + (size_t)(s0 + r) * 64 + cb);
    *(s16x8*)&L[r][cb + 8] = *(const s16x8*)(V + base + (size_t)(s0 + r) * 64 + cb + 8);
    __syncthreads();

    s16x8 o0, o1;
    #pragma unroll
    for (int k = 0; k < 8; ++k) o0[k] = (short)L[cb + k][r];
    #pragma unroll
    for (int k = 0; k < 8; ++k) o1[k] = (short)L[cb + 8 + k][r];
    *(s16x8*)(VT + base + (size_t)r * S_ + s0 + cb)     = o0;
    *(s16x8*)(VT + base + (size_t)r * S_ + s0 + cb + 8) = o1;
}

// ---------------------------------------------------------------------------
// Flash attention bf16.  Block = (q-tile 64, h, b), 4 waves, wave owns 16 q.
// K/VT tiles 64-wide in LDS, XOR-swizzled 16B slots; P wave-private swizzled.
// Softmax fp32 in-register (16-lane shfl groups).  Q frags hoisted (scaled).
// ---------------------------------------------------------------------------
__global__ __launch_bounds__(256)
void attn_bf16(const ushort* __restrict__ Q, const ushort* __restrict__ K,
               const ushort* __restrict__ VT, const int* __restrict__ mask,
               ushort* __restrict__ ctx)
{
    __shared__ ushort Ks[64 * 64];     // [key][hd]  swizzled
    __shared__ ushort Vs[64 * 64];     // [hd][key]  swizzled
    __shared__ ushort Ps[4][16 * 64];  // per-wave [q][key] swizzled

    const int t = threadIdx.x;
    const int lane = t & 63, w = t >> 6;
    const int lrow = lane & 15, lk = lane >> 4;
    const int q0 = blockIdx.x * 64, h = blockIdx.y, b = blockIdx.z;

    const ushort* Qh = Q + ((size_t)(b * H_ + h)) * S_ * HD_;
    const ushort* Kh = K + ((size_t)(b * H_ + h)) * S_ * HD_;
    const ushort* Vh = VT + ((size_t)(b * H_ + h)) * HD_ * S_;
    const int* mrow = mask + b * S_;

    s16x8 qf[2];
    qf[0] = *(const s16x8*)(Qh + (q0 + w * 16 + lrow) * 64 + lk * 8);
    qf[1] = *(const s16x8*)(Qh + (q0 + w * 16 + lrow) * 64 + 32 + lk * 8);

    f32x4 O[4];
    #pragma unroll
    for (int nt = 0; nt < 4; ++nt) O[nt] = (f32x4)0.f;
    float m_run[4] = {-INFINITY, -INFINITY, -INFINITY, -INFINITY};
    float l_run[4] = {0.f, 0.f, 0.f, 0.f};

    for (int k0 = 0; k0 < S_; k0 += 64) {
        __syncthreads();
        #pragma unroll
        for (int p = 0; p < 2; ++p) {           // stage K + VT (512 chunks each)
            const int c = t + p * 256;
            const int row = c >> 3, slot = c & 7;
            const s16x8 kv = *(const s16x8*)(Kh + (size_t)(k0 + row) * 64 + slot * 8);
            *(s16x8*)(Ks + row * 64 + ((slot ^ (row & 7)) * 8)) = kv;
            const s16x8 vv = *(const s16x8*)(Vh + (size_t)row * S_ + k0 + slot * 8);
            *(s16x8*)(Vs + row * 64 + ((slot ^ (row & 7)) * 8)) = vv;
        }
        __syncthreads();

        // QK^T -> sc[nt] : rows lk*4+r, col nt*16+lrow
        f32x4 sc[4];
        #pragma unroll
        for (int nt = 0; nt < 4; ++nt) sc[nt] = (f32x4)0.f;
        #pragma unroll
        for (int kk = 0; kk < 2; ++kk)
            #pragma unroll
            for (int nt = 0; nt < 4; ++nt) {
                const int krow = nt * 16 + lrow;
                const s16x8 kf = *(const s16x8*)(Ks + krow * 64 + (((kk * 4 + lk) ^ (krow & 7)) * 8));
                sc[nt] = MFMA16(qf[kk], kf, sc[nt]);
            }

        int km[4];
        #pragma unroll
        for (int nt = 0; nt < 4; ++nt) km[nt] = mrow[k0 + nt * 16 + lrow];

        float pv[4][4];                         // [r][nt]
        #pragma unroll
        for (int r = 0; r < 4; ++r) {
            float s4[4];
            #pragma unroll
            for (int nt = 0; nt < 4; ++nt) s4[nt] = km[nt] ? sc[nt][r] : BIG_NEG_;
            float vmax = fmaxf(fmaxf(s4[0], s4[1]), fmaxf(s4[2], s4[3]));
            vmax = fmaxf(vmax, __shfl_xor(vmax, 1));
            vmax = fmaxf(vmax, __shfl_xor(vmax, 2));
            vmax = fmaxf(vmax, __shfl_xor(vmax, 4));
            vmax = fmaxf(vmax, __shfl_xor(vmax, 8));
            const float mn = fmaxf(m_run[r], vmax);
            const float corr = __expf(m_run[r] - mn);
            m_run[r] = mn;
            float rs = 0.f;
            #pragma unroll
            for (int nt = 0; nt < 4; ++nt) { pv[r][nt] = __expf(s4[nt] - mn); rs += pv[r][nt]; }
            rs += __shfl_xor(rs, 1);
            rs += __shfl_xor(rs, 2);
            rs += __shfl_xor(rs, 4);
            rs += __shfl_xor(rs, 8);
            l_run[r] = l_run[r] * corr + rs;
            #pragma unroll
            for (int nt = 0; nt < 4; ++nt) O[nt][r] *= corr;
        }

        // P -> LDS (wave-private, swizzled), then PV MFMAs
        #pragma unroll
        for (int r = 0; r < 4; ++r) {
            const int q = lk * 4 + r;
            #pragma unroll
            for (int nt = 0; nt < 4; ++nt) {
                const int key = nt * 16 + lrow;
                Ps[w][q * 64 + (((key >> 3) ^ (q & 7)) * 8) + (key & 7)] = f2b(pv[r][nt]);
            }
        }
        #pragma unroll
        for (int kk = 0; kk < 2; ++kk) {
            const s16x8 pa = *(const s16x8*)(&Ps[w][lrow * 64 + (((kk * 4 + lk) ^ (lrow & 7)) * 8)]);
            #pragma unroll
            for (int nt = 0; nt < 4; ++nt) {
                const int vrow = nt * 16 + lrow;
                const s16x8 vf = *(const s16x8*)(Vs + vrow * 64 + (((kk * 4 + lk) ^ (vrow & 7)) * 8));
                O[nt] = MFMA16(pa, vf, O[nt]);
            }
        }
    }

    #pragma unroll
    for (int r = 0; r < 4; ++r) {
        const float inv = 1.f / l_run[r];
        const int s = q0 + w * 16 + lk * 4 + r;
        #pragma unroll
        for (int nt = 0; nt < 4; ++nt)
            ctx[((size_t)(b * S_ + s)) * D_ + h * 64 + nt * 16 + lrow] = f2b(O[nt][r] * inv);
    }
}

extern "C" void kernel_launch(void* const* d_in, const int* in_sizes, int n_in,
                              void* d_out, int out_size, void* d_ws, size_t ws_size,
                              hipStream_t stream) {
    const float* hidden = (const float*)d_in[0];
    const int*   mask   = (const int*)d_in[1];
    const float* Wq = (const float*)d_in[2];
    const float* bq = (const float*)d_in[3];
    const float* Wk = (const float*)d_in[4];
    const float* bk = (const float*)d_in[5];
    const float* Wv = (const float*)d_in[6];
    const float* bv = (const float*)d_in[7];
    const float* Wo = (const float*)d_in[8];
    const float* bo = (const float*)d_in[9];
    float* out = (float*)d_out;

    ushort* ws = (ushort*)d_ws;
    const size_t T = (size_t)B_ * H_ * S_ * HD_;   // 8388608 elems
    ushort* Qb  = ws;
    ushort* Kb  = ws + T;
    ushort* Vb  = ws + 2 * T;
    ushort* VTb = ws + 3 * T;
    ushort* Cb  = ws + 4 * T;                       // ctx bf16 [B,S,D]

    const dim3 gg(64, 8), bb(256);
    gemm_bf16<0><<<gg, bb, 0, stream>>>(hidden, nullptr, Wq, bq, mask, nullptr, Qb);
    gemm_bf16<1><<<gg, bb, 0, stream>>>(hidden, nullptr, Wk, bk, mask, nullptr, Kb);
    gemm_bf16<2><<<gg, bb, 0, stream>>>(hidden, nullptr, Wv, bv, mask, nullptr, Vb);
    transpose_v<<<dim3(S_ / 64, H_, B_), bb, 0, stream>>>(Vb, VTb);
    attn_bf16<<<dim3(S_ / 64, H_, B_), bb, 0, stream>>>(Qb, Kb, VTb, mask, Cb);
    gemm_bf16<3><<<gg, bb, 0, stream>>>(nullptr, Cb, Wo, bo, mask, out, nullptr);
}

// Round 5
// 457.906 us; speedup vs baseline: 4.1740x; 1.0642x over previous
//
#include <hip/hip_runtime.h>
#include <math.h>

// ---------------------------------------------------------------------------
// Masked MHA, bf16-MFMA pipeline v2.  B=4 S=2048 D=1024 H=16 HD=64
//  0. convert_all: hidden*mask -> Xb bf16; Wq|Wk|Wv|Wo -> Wb bf16
//  1. qkv_gemm   : fused 3-in-1 m97-style GEMM (global_load_lds w16),
//                  Q pre-scaled by SCALE*log2(e)  -> Q/K/V bf16 [B,H,S,HD]
//  2. transpose_v: V -> VT [B,H,HD,S]
//  3. attn_bf16  : flash, MFMA QK^T+PV, exp2 softmax, defer-max (THR=8),
//                  T14 reg-prefetch staging -> ctx bf16 [B,S,D]
//  4. out_gemm   : ctx @ Wo^T + bo, query-mask -> f32 out
// MFMA 16x16x32_bf16 layouts (verified round 4):
//   A/B: lane supplies row/col (l&15), k=(l>>4)*8+j ;  C/D: col=l&15, row=(l>>4)*4+reg
// ---------------------------------------------------------------------------

typedef __attribute__((ext_vector_type(4))) float f32x4;
typedef __attribute__((ext_vector_type(8))) short s16x8;

#define MFMA16(a, b, c) __builtin_amdgcn_mfma_f32_16x16x32_bf16((a), (b), (c), 0, 0, 0)

constexpr int B_ = 4, S_ = 2048, D_ = 1024, H_ = 16, HD_ = 64;
constexpr float SCALE_ = 0.125f;
constexpr float LOG2E_ = 1.4426950408889634f;
constexpr float BIG_NEG_ = -1e9f;      // log2-domain "minus infinity"
constexpr float DEFER_THR_ = 8.f;      // T13: P bounded by 2^8

__device__ __forceinline__ ushort f2b(float x) {   // f32 -> bf16 bits, RNE
    unsigned u = __float_as_uint(x);
    return (ushort)((u + 0x7FFFu + ((u >> 16) & 1u)) >> 16);
}

__device__ __forceinline__ void gload16(const ushort* g, ushort* l) {
    __builtin_amdgcn_global_load_lds(
        (const __attribute__((address_space(1))) void*)g,
        (__attribute__((address_space(3))) void*)l, 16, 0, 0);
}

// ---------------------------------------------------------------------------
// 0. convert: X (masked) and 4 weight matrices -> bf16, 8 elems/thread chunks
// ---------------------------------------------------------------------------
__global__ __launch_bounds__(256)
void convert_all(const float* __restrict__ hidden, const int* __restrict__ mask,
                 const float* __restrict__ Wq, const float* __restrict__ Wk,
                 const float* __restrict__ Wv, const float* __restrict__ Wo,
                 ushort* __restrict__ Xb, ushort* __restrict__ Wb)
{
    const int NXC = 1048576;                  // 8.4M X elems / 8
    const int NWC = 131072;                   // 1M W elems / 8
    const int TOT = NXC + 4 * NWC;
    for (int idx = blockIdx.x * 256 + threadIdx.x; idx < TOT; idx += gridDim.x * 256) {
        if (idx < NXC) {
            const size_t e = (size_t)idx * 8;
            const float mf = (float)mask[e >> 10];
            const float4 a = *(const float4*)(hidden + e);
            const float4 b = *(const float4*)(hidden + e + 4);
            s16x8 v;
            v[0] = (short)f2b(a.x * mf); v[1] = (short)f2b(a.y * mf);
            v[2] = (short)f2b(a.z * mf); v[3] = (short)f2b(a.w * mf);
            v[4] = (short)f2b(b.x * mf); v[5] = (short)f2b(b.y * mf);
            v[6] = (short)f2b(b.z * mf); v[7] = (short)f2b(b.w * mf);
            *(s16x8*)(Xb + e) = v;
        } else {
            const int c = idx - NXC;
            const int sel = c >> 17;
            const size_t off = (size_t)(c & (NWC - 1)) * 8;
            const float* src = (sel == 0) ? Wq : (sel == 1) ? Wk : (sel == 2) ? Wv : Wo;
            const float4 a = *(const float4*)(src + off);
            const float4 b = *(const float4*)(src + off + 4);
            s16x8 v;
            v[0] = (short)f2b(a.x); v[1] = (short)f2b(a.y);
            v[2] = (short)f2b(a.z); v[3] = (short)f2b(a.w);
            v[4] = (short)f2b(b.x); v[5] = (short)f2b(b.y);
            v[6] = (short)f2b(b.z); v[7] = (short)f2b(b.w);
            *(s16x8*)(Wb + (size_t)sel * 1048576 + off) = v;
        }
    }
}

// ---------------------------------------------------------------------------
// 1. fused QKV GEMM, m97-style: 128x128 tile, BK=64, global_load_lds w16.
//    grid (64, 24): y>>3 selects Q/K/V, y&7 the n-block.
// ---------------------------------------------------------------------------
__global__ __launch_bounds__(256)
void qkv_gemm(const ushort* __restrict__ Xb, const ushort* __restrict__ Wall,
              const float* __restrict__ bq, const float* __restrict__ bk,
              const float* __restrict__ bv,
              ushort* __restrict__ Qb, ushort* __restrict__ Kb,
              ushort* __restrict__ Vb)
{
    __shared__ ushort As[128 * 64];
    __shared__ ushort Bs[128 * 64];

    const int t = threadIdx.x;
    const int lane = t & 63;
    const int w = t >> 6, wr = w >> 1, wc = w & 1;
    const int lrow = lane & 15, lk = lane >> 4;
    const int m0 = blockIdx.x * 128;
    const int sel = blockIdx.y >> 3;
    const int n0 = (blockIdx.y & 7) * 128;

    const ushort* Wb = Wall + (size_t)sel * 1048576;
    const float* bias = (sel == 0) ? bq : (sel == 1) ? bk : bv;
    ushort* Out = (sel == 0) ? Qb : (sel == 1) ? Kb : Vb;
    const float escale = (sel == 0) ? SCALE_ * LOG2E_ : 1.f;

    f32x4 acc[4][4];
    #pragma unroll
    for (int i = 0; i < 4; ++i)
        #pragma unroll
        for (int j = 0; j < 4; ++j) acc[i][j] = (f32x4)0.f;

    for (int k0 = 0; k0 < D_; k0 += 64) {
        __syncthreads();
        #pragma unroll
        for (int p = 0; p < 4; ++p) {
            const int c = p * 256 + t;
            const int row = c >> 3, slot = c & 7;
            ushort* dst_base_a = As + (size_t)(p * 256 + (t & 192)) * 8;  // wave-uniform
            ushort* dst_base_b = Bs + (size_t)(p * 256 + (t & 192)) * 8;
            gload16(Xb + (size_t)(m0 + row) * 1024 + k0 + slot * 8, dst_base_a);
            gload16(Wb + (size_t)(n0 + row) * 1024 + k0 + slot * 8, dst_base_b);
        }
        __syncthreads();

        #pragma unroll
        for (int kk = 0; kk < 2; ++kk) {
            s16x8 af[4], bf[4];
            #pragma unroll
            for (int i = 0; i < 4; ++i)
                af[i] = *(const s16x8*)(As + (wr * 64 + i * 16 + lrow) * 64 + kk * 32 + lk * 8);
            #pragma unroll
            for (int j = 0; j < 4; ++j)
                bf[j] = *(const s16x8*)(Bs + (wc * 64 + j * 16 + lrow) * 64 + kk * 32 + lk * 8);
            #pragma unroll
            for (int i = 0; i < 4; ++i)
                #pragma unroll
                for (int j = 0; j < 4; ++j)
                    acc[i][j] = MFMA16(af[i], bf[j], acc[i][j]);
        }
    }

    #pragma unroll
    for (int i = 0; i < 4; ++i) {
        #pragma unroll
        for (int j = 0; j < 4; ++j) {
            const int gn = n0 + wc * 64 + j * 16 + lrow;
            const float bb = bias[gn];
            const int h_ = gn >> 6, hd_ = gn & 63;
            #pragma unroll
            for (int r = 0; r < 4; ++r) {
                const int gm = m0 + wr * 64 + i * 16 + lk * 4 + r;
                const float v = (acc[i][j][r] + bb) * escale;
                const int b_ = gm >> 11, s_ = gm & (S_ - 1);
                Out[(((size_t)(b_ * H_ + h_)) * S_ + s_) * HD_ + hd_] = f2b(v);
            }
        }
    }
}

// ---------------------------------------------------------------------------
// 2. V [B,H,S,HD] -> VT [B,H,HD,S]
// ---------------------------------------------------------------------------
__global__ __launch_bounds__(256)
void transpose_v(const ushort* __restrict__ V, ushort* __restrict__ VT)
{
    __shared__ ushort L[64][72];
    const int t = threadIdx.x;
    const int s0 = blockIdx.x * 64;
    const size_t base = ((size_t)(blockIdx.z * H_ + blockIdx.y)) * S_ * HD_;
    const int r = t >> 2, cb = (t & 3) * 16;

    *(s16x8*)&L[r][cb]     = *(const s16x8*)(V + base + (size_t)(s0 + r) * 64 + cb);
    *(s16x8*)&L[r][cb + 8] = *(const s16x8*)(V + base + (size_t)(s0 + r) * 64 + cb + 8);
    __syncthreads();

    s16x8 o0, o1;
    #pragma unroll
    for (int k = 0; k < 8; ++k) o0[k] = (short)L[cb + k][r];
    #pragma unroll
    for (int k = 0; k < 8; ++k) o1[k] = (short)L[cb + 8 + k][r];
    *(s16x8*)(VT + base + (size_t)r * S_ + s0 + cb)     = o0;
    *(s16x8*)(VT + base + (size_t)r * S_ + s0 + cb + 8) = o1;
}

// ---------------------------------------------------------------------------
// 3. Flash attention bf16: exp2 softmax (Q pre-scaled by SCALE*log2e),
//    defer-max THR=8, T14 reg-prefetch of next K/V tile.
// ---------------------------------------------------------------------------
__global__ __launch_bounds__(256)
void attn_bf16(const ushort* __restrict__ Q, const ushort* __restrict__ K,
               const ushort* __restrict__ VT, const int* __restrict__ mask,
               ushort* __restrict__ ctx)
{
    __shared__ ushort Ks[64 * 64];     // [key][hd]  swizzled
    __shared__ ushort Vs[64 * 64];     // [hd][key]  swizzled
    __shared__ ushort Ps[4][16 * 64];  // per-wave [q][key] swizzled

    const int t = threadIdx.x;
    const int lane = t & 63, w = t >> 6;
    const int lrow = lane & 15, lk = lane >> 4;
    const int q0 = blockIdx.x * 64, h = blockIdx.y, b = blockIdx.z;

    const ushort* Qh = Q + ((size_t)(b * H_ + h)) * S_ * HD_;
    const ushort* Kh = K + ((size_t)(b * H_ + h)) * S_ * HD_;
    const ushort* Vh = VT + ((size_t)(b * H_ + h)) * HD_ * S_;
    const int* mrow = mask + b * S_;

    s16x8 qf[2];
    qf[0] = *(const s16x8*)(Qh + (q0 + w * 16 + lrow) * 64 + lk * 8);
    qf[1] = *(const s16x8*)(Qh + (q0 + w * 16 + lrow) * 64 + 32 + lk * 8);

    f32x4 O[4];
    #pragma unroll
    for (int nt = 0; nt < 4; ++nt) O[nt] = (f32x4)0.f;
    float m_run[4] = {-INFINITY, -INFINITY, -INFINITY, -INFINITY};
    float l_run[4] = {0.f, 0.f, 0.f, 0.f};

    // T14 prologue: issue tile-0 loads to regs
    const int srow0 = t >> 3,           sslot0 = t & 7;
    const int srow1 = (t + 256) >> 3,   sslot1 = t & 7;   // (t+256)&7 == t&7
    s16x8 kreg0, kreg1, vreg0, vreg1;
    kreg0 = *(const s16x8*)(Kh + (size_t)srow0 * 64 + sslot0 * 8);
    kreg1 = *(const s16x8*)(Kh + (size_t)srow1 * 64 + sslot1 * 8);
    vreg0 = *(const s16x8*)(Vh + (size_t)srow0 * S_ + sslot0 * 8);
    vreg1 = *(const s16x8*)(Vh + (size_t)srow1 * S_ + sslot1 * 8);

    for (int k0 = 0; k0 < S_; k0 += 64) {
        __syncthreads();   // previous tile's consumers done
        *(s16x8*)(Ks + srow0 * 64 + ((sslot0 ^ (srow0 & 7)) * 8)) = kreg0;
        *(s16x8*)(Ks + srow1 * 64 + ((sslot1 ^ (srow1 & 7)) * 8)) = kreg1;
        *(s16x8*)(Vs + srow0 * 64 + ((sslot0 ^ (srow0 & 7)) * 8)) = vreg0;
        *(s16x8*)(Vs + srow1 * 64 + ((sslot1 ^ (srow1 & 7)) * 8)) = vreg1;
        __syncthreads();

        // T14: issue next tile's global loads now; consumed next iteration
        if (k0 + 64 < S_) {
            kreg0 = *(const s16x8*)(Kh + (size_t)(k0 + 64 + srow0) * 64 + sslot0 * 8);
            kreg1 = *(const s16x8*)(Kh + (size_t)(k0 + 64 + srow1) * 64 + sslot1 * 8);
            vreg0 = *(const s16x8*)(Vh + (size_t)srow0 * S_ + k0 + 64 + sslot0 * 8);
            vreg1 = *(const s16x8*)(Vh + (size_t)srow1 * S_ + k0 + 64 + sslot1 * 8);
        }

        // QK^T (scores already in log2 domain via Q pre-scale)
        f32x4 sc[4];
        #pragma unroll
        for (int nt = 0; nt < 4; ++nt) sc[nt] = (f32x4)0.f;
        #pragma unroll
        for (int kk = 0; kk < 2; ++kk)
            #pragma unroll
            for (int nt = 0; nt < 4; ++nt) {
                const int krow = nt * 16 + lrow;
                const s16x8 kf = *(const s16x8*)(Ks + krow * 64 + (((kk * 4 + lk) ^ (krow & 7)) * 8));
                sc[nt] = MFMA16(qf[kk], kf, sc[nt]);
            }

        int km[4];
        #pragma unroll
        for (int nt = 0; nt < 4; ++nt) km[nt] = mrow[k0 + nt * 16 + lrow];

        float s4[4][4], vmax[4];               // [r][nt]
        #pragma unroll
        for (int r = 0; r < 4; ++r) {
            #pragma unroll
            for (int nt = 0; nt < 4; ++nt) s4[r][nt] = km[nt] ? sc[nt][r] : BIG_NEG_;
            float tm = fmaxf(fmaxf(s4[r][0], s4[r][1]), fmaxf(s4[r][2], s4[r][3]));
            tm = fmaxf(tm, __shfl_xor(tm, 1));
            tm = fmaxf(tm, __shfl_xor(tm, 2));
            tm = fmaxf(tm, __shfl_xor(tm, 4));
            tm = fmaxf(tm, __shfl_xor(tm, 8));
            vmax[r] = tm;
        }

        // T13 defer-max: rescale only if any row grew past THR
        float g = vmax[0] - m_run[0];
        #pragma unroll
        for (int r = 1; r < 4; ++r) g = fmaxf(g, vmax[r] - m_run[r]);
        if (!__all(g <= DEFER_THR_)) {
            #pragma unroll
            for (int r = 0; r < 4; ++r) {
                const float mn = fmaxf(m_run[r], vmax[r]);
                const float corr = exp2f(m_run[r] - mn);   // 0 on first tile
                m_run[r] = mn;
                l_run[r] *= corr;
                #pragma unroll
                for (int nt = 0; nt < 4; ++nt) O[nt][r] *= corr;
            }
        }

        float pv[4][4];
        #pragma unroll
        for (int r = 0; r < 4; ++r) {
            float rs = 0.f;
            #pragma unroll
            for (int nt = 0; nt < 4; ++nt) {
                pv[r][nt] = exp2f(s4[r][nt] - m_run[r]);   // bounded by 2^THR
                rs += pv[r][nt];
            }
            rs += __shfl_xor(rs, 1);
            rs += __shfl_xor(rs, 2);
            rs += __shfl_xor(rs, 4);
            rs += __shfl_xor(rs, 8);
            l_run[r] += rs;
        }

        // P -> LDS (wave-private, swizzled), then PV MFMAs
        #pragma unroll
        for (int r = 0; r < 4; ++r) {
            const int q = lk * 4 + r;
            #pragma unroll
            for (int nt = 0; nt < 4; ++nt) {
                const int key = nt * 16 + lrow;
                Ps[w][q * 64 + (((key >> 3) ^ (q & 7)) * 8) + (key & 7)] = f2b(pv[r][nt]);
            }
        }
        #pragma unroll
        for (int kk = 0; kk < 2; ++kk) {
            const s16x8 pa = *(const s16x8*)(&Ps[w][lrow * 64 + (((kk * 4 + lk) ^ (lrow & 7)) * 8)]);
            #pragma unroll
            for (int nt = 0; nt < 4; ++nt) {
                const int vrow = nt * 16 + lrow;
                const s16x8 vf = *(const s16x8*)(Vs + vrow * 64 + (((kk * 4 + lk) ^ (vrow & 7)) * 8));
                O[nt] = MFMA16(pa, vf, O[nt]);
            }
        }
    }

    #pragma unroll
    for (int r = 0; r < 4; ++r) {
        const float inv = 1.f / l_run[r];
        const int s = q0 + w * 16 + lk * 4 + r;
        #pragma unroll
        for (int nt = 0; nt < 4; ++nt)
            ctx[((size_t)(b * S_ + s)) * D_ + h * 64 + nt * 16 + lrow] = f2b(O[nt][r] * inv);
    }
}

// ---------------------------------------------------------------------------
// 4. out GEMM: ctx(bf16) @ Wo^T + bo, row-mask, f32 out.  m97-style staging.
// ---------------------------------------------------------------------------
__global__ __launch_bounds__(256)
void out_gemm(const ushort* __restrict__ Xb, const ushort* __restrict__ Wb,
              const float* __restrict__ bias, const int* __restrict__ mask,
              float* __restrict__ Cf)
{
    __shared__ ushort As[128 * 64];
    __shared__ ushort Bs[128 * 64];

    const int t = threadIdx.x;
    const int lane = t & 63;
    const int w = t >> 6, wr = w >> 1, wc = w & 1;
    const int lrow = lane & 15, lk = lane >> 4;
    const int m0 = blockIdx.x * 128, n0 = blockIdx.y * 128;

    f32x4 acc[4][4];
    #pragma unroll
    for (int i = 0; i < 4; ++i)
        #pragma unroll
        for (int j = 0; j < 4; ++j) acc[i][j] = (f32x4)0.f;

    for (int k0 = 0; k0 < D_; k0 += 64) {
        __syncthreads();
        #pragma unroll
        for (int p = 0; p < 4; ++p) {
            const int c = p * 256 + t;
            const int row = c >> 3, slot = c & 7;
            gload16(Xb + (size_t)(m0 + row) * 1024 + k0 + slot * 8,
                    As + (size_t)(p * 256 + (t & 192)) * 8);
            gload16(Wb + (size_t)(n0 + row) * 1024 + k0 + slot * 8,
                    Bs + (size_t)(p * 256 + (t & 192)) * 8);
        }
        __syncthreads();

        #pragma unroll
        for (int kk = 0; kk < 2; ++kk) {
            s16x8 af[4], bf[4];
            #pragma unroll
            for (int i = 0; i < 4; ++i)
                af[i] = *(const s16x8*)(As + (wr * 64 + i * 16 + lrow) * 64 + kk * 32 + lk * 8);
            #pragma unroll
            for (int j = 0; j < 4; ++j)
                bf[j] = *(const s16x8*)(Bs + (wc * 64 + j * 16 + lrow) * 64 + kk * 32 + lk * 8);
            #pragma unroll
            for (int i = 0; i < 4; ++i)
                #pragma unroll
                for (int j = 0; j < 4; ++j)
                    acc[i][j] = MFMA16(af[i], bf[j], acc[i][j]);
        }
    }

    #pragma unroll
    for (int i = 0; i < 4; ++i) {
        #pragma unroll
        for (int j = 0; j < 4; ++j) {
            const int gn = n0 + wc * 64 + j * 16 + lrow;
            const float bb = bias[gn];
            #pragma unroll
            for (int r = 0; r < 4; ++r) {
                const int gm = m0 + wr * 64 + i * 16 + lk * 4 + r;
                const float v = (acc[i][j][r] + bb) * (float)mask[gm];
                Cf[(size_t)gm * 1024 + gn] = v;
            }
        }
    }
}

extern "C" void kernel_launch(void* const* d_in, const int* in_sizes, int n_in,
                              void* d_out, int out_size, void* d_ws, size_t ws_size,
                              hipStream_t stream) {
    const float* hidden = (const float*)d_in[0];
    const int*   mask   = (const int*)d_in[1];
    const float* Wq = (const float*)d_in[2];
    const float* bq = (const float*)d_in[3];
    const float* Wk = (const float*)d_in[4];
    const float* bk = (const float*)d_in[5];
    const float* Wv = (const float*)d_in[6];
    const float* bv = (const float*)d_in[7];
    const float* Wo = (const float*)d_in[8];
    const float* bo = (const float*)d_in[9];
    float* out = (float*)d_out;

    ushort* ws = (ushort*)d_ws;
    const size_t T = (size_t)B_ * H_ * S_ * HD_;   // 8388608 elems
    ushort* Xb  = ws;                               // [8192][1024] bf16
    ushort* Wb  = ws + T;                           // 4 x [1024][1024] bf16
    ushort* Qb  = ws + T + 4194304;
    ushort* Kb  = Qb + T;
    ushort* Vb  = Kb + T;
    ushort* VTb = Vb + T;
    ushort* Cb  = VTb + T;                          // ctx bf16 [B,S,D]

    const dim3 bb(256);
    convert_all<<<2048, bb, 0, stream>>>(hidden, mask, Wq, Wk, Wv, Wo, Xb, Wb);
    qkv_gemm<<<dim3(64, 24), bb, 0, stream>>>(Xb, Wb, bq, bk, bv, Qb, Kb, Vb);
    transpose_v<<<dim3(S_ / 64, H_, B_), bb, 0, stream>>>(Vb, VTb);
    attn_bf16<<<dim3(S_ / 64, H_, B_), bb, 0, stream>>>(Qb, Kb, VTb, mask, Cb);
    out_gemm<<<dim3(64, 8), bb, 0, stream>>>(Cb, Wb + 3 * 1048576, bo, mask, out);
}

// Round 10
// 386.699 us; speedup vs baseline: 4.9426x; 1.1841x over previous
//
#include <hip/hip_runtime.h>
#include <math.h>

// ---------------------------------------------------------------------------
// Masked MHA, bf16-MFMA pipeline v3.  B=4 S=2048 D=1024 H=16 HD=64
//  0. convert_all: hidden*mask -> Xb bf16; Wq|Wk|Wv|Wo -> Wb bf16
//  1. qkv_gemm   : fused 3-in-1 GEMM (global_load_lds w16), Q pre-scaled by
//                  SCALE*log2(e)  -> Q/K/V bf16 [B,H,S,HD]
//  2. transpose_v: V -> VT [B,H,HD,S]
//  3. attn_bf16  : flash, SWAPPED QK^T (lane owns one q-row -> 2-shfl
//                  reductions), exp2 softmax, defer-max THR=8, paired b64
//                  P writes -> ctx bf16 [B,S,D]
//  4. out_gemm   : ctx @ Wo^T + bo, query-mask -> f32 out
// MFMA 16x16x32_bf16 layouts (verified rounds 4-5):
//   A: row=l&15, k=(l>>4)*8+j ; B: col=l&15, k=(l>>4)*8+j ;
//   C/D: col=l&15, row=(l>>4)*4+reg
// ---------------------------------------------------------------------------

typedef __attribute__((ext_vector_type(4))) float f32x4;
typedef __attribute__((ext_vector_type(8))) short s16x8;

#define MFMA16(a, b, c) __builtin_amdgcn_mfma_f32_16x16x32_bf16((a), (b), (c), 0, 0, 0)

constexpr int B_ = 4, S_ = 2048, D_ = 1024, H_ = 16, HD_ = 64;
constexpr float SCALE_ = 0.125f;
constexpr float LOG2E_ = 1.4426950408889634f;
constexpr float BIG_NEG_ = -1e9f;      // log2-domain "minus infinity"
constexpr float DEFER_THR_ = 8.f;      // T13: P bounded by 2^8

__device__ __forceinline__ ushort f2b(float x) {   // f32 -> bf16 bits, RNE
    unsigned u = __float_as_uint(x);
    return (ushort)((u + 0x7FFFu + ((u >> 16) & 1u)) >> 16);
}

__device__ __forceinline__ void gload16(const ushort* g, ushort* l) {
    __builtin_amdgcn_global_load_lds(
        (const __attribute__((address_space(1))) void*)g,
        (__attribute__((address_space(3))) void*)l, 16, 0, 0);
}

// ---------------------------------------------------------------------------
// 0. convert: X (masked) and 4 weight matrices -> bf16
// ---------------------------------------------------------------------------
__global__ __launch_bounds__(256)
void convert_all(const float* __restrict__ hidden, const int* __restrict__ mask,
                 const float* __restrict__ Wq, const float* __restrict__ Wk,
                 const float* __restrict__ Wv, const float* __restrict__ Wo,
                 ushort* __restrict__ Xb, ushort* __restrict__ Wb)
{
    const int NXC = 1048576;                  // 8.4M X elems / 8
    const int NWC = 131072;                   // 1M W elems / 8
    const int TOT = NXC + 4 * NWC;
    for (int idx = blockIdx.x * 256 + threadIdx.x; idx < TOT; idx += gridDim.x * 256) {
        if (idx < NXC) {
            const size_t e = (size_t)idx * 8;
            const float mf = (float)mask[e >> 10];
            const float4 a = *(const float4*)(hidden + e);
            const float4 b = *(const float4*)(hidden + e + 4);
            s16x8 v;
            v[0] = (short)f2b(a.x * mf); v[1] = (short)f2b(a.y * mf);
            v[2] = (short)f2b(a.z * mf); v[3] = (short)f2b(a.w * mf);
            v[4] = (short)f2b(b.x * mf); v[5] = (short)f2b(b.y * mf);
            v[6] = (short)f2b(b.z * mf); v[7] = (short)f2b(b.w * mf);
            *(s16x8*)(Xb + e) = v;
        } else {
            const int c = idx - NXC;
            const int sel = c >> 17;
            const size_t off = (size_t)(c & (NWC - 1)) * 8;
            const float* src = (sel == 0) ? Wq : (sel == 1) ? Wk : (sel == 2) ? Wv : Wo;
            const float4 a = *(const float4*)(src + off);
            const float4 b = *(const float4*)(src + off + 4);
            s16x8 v;
            v[0] = (short)f2b(a.x); v[1] = (short)f2b(a.y);
            v[2] = (short)f2b(a.z); v[3] = (short)f2b(a.w);
            v[4] = (short)f2b(b.x); v[5] = (short)f2b(b.y);
            v[6] = (short)f2b(b.z); v[7] = (short)f2b(b.w);
            *(s16x8*)(Wb + (size_t)sel * 1048576 + off) = v;
        }
    }
}

// ---------------------------------------------------------------------------
// 1. fused QKV GEMM, 128x128 tile, BK=64, global_load_lds w16.
// ---------------------------------------------------------------------------
__global__ __launch_bounds__(256)
void qkv_gemm(const ushort* __restrict__ Xb, const ushort* __restrict__ Wall,
              const float* __restrict__ bq, const float* __restrict__ bk,
              const float* __restrict__ bv,
              ushort* __restrict__ Qb, ushort* __restrict__ Kb,
              ushort* __restrict__ Vb)
{
    __shared__ ushort As[128 * 64];
    __shared__ ushort Bs[128 * 64];

    const int t = threadIdx.x;
    const int lane = t & 63;
    const int w = t >> 6, wr = w >> 1, wc = w & 1;
    const int lrow = lane & 15, lk = lane >> 4;
    const int m0 = blockIdx.x * 128;
    const int sel = blockIdx.y >> 3;
    const int n0 = (blockIdx.y & 7) * 128;

    const ushort* Wb = Wall + (size_t)sel * 1048576;
    const float* bias = (sel == 0) ? bq : (sel == 1) ? bk : bv;
    ushort* Out = (sel == 0) ? Qb : (sel == 1) ? Kb : Vb;
    const float escale = (sel == 0) ? SCALE_ * LOG2E_ : 1.f;

    f32x4 acc[4][4];
    #pragma unroll
    for (int i = 0; i < 4; ++i)
        #pragma unroll
        for (int j = 0; j < 4; ++j) acc[i][j] = (f32x4)0.f;

    for (int k0 = 0; k0 < D_; k0 += 64) {
        __syncthreads();
        #pragma unroll
        for (int p = 0; p < 4; ++p) {
            const int c = p * 256 + t;
            const int row = c >> 3, slot = c & 7;
            gload16(Xb + (size_t)(m0 + row) * 1024 + k0 + slot * 8,
                    As + (size_t)(p * 256 + (t & 192)) * 8);
            gload16(Wb + (size_t)(n0 + row) * 1024 + k0 + slot * 8,
                    Bs + (size_t)(p * 256 + (t & 192)) * 8);
        }
        __syncthreads();

        #pragma unroll
        for (int kk = 0; kk < 2; ++kk) {
            s16x8 af[4], bf[4];
            #pragma unroll
            for (int i = 0; i < 4; ++i)
                af[i] = *(const s16x8*)(As + (wr * 64 + i * 16 + lrow) * 64 + kk * 32 + lk * 8);
            #pragma unroll
            for (int j = 0; j < 4; ++j)
                bf[j] = *(const s16x8*)(Bs + (wc * 64 + j * 16 + lrow) * 64 + kk * 32 + lk * 8);
            #pragma unroll
            for (int i = 0; i < 4; ++i)
                #pragma unroll
                for (int j = 0; j < 4; ++j)
                    acc[i][j] = MFMA16(af[i], bf[j], acc[i][j]);
        }
    }

    #pragma unroll
    for (int i = 0; i < 4; ++i) {
        #pragma unroll
        for (int j = 0; j < 4; ++j) {
            const int gn = n0 + wc * 64 + j * 16 + lrow;
            const float bb = bias[gn];
            const int h_ = gn >> 6, hd_ = gn & 63;
            #pragma unroll
            for (int r = 0; r < 4; ++r) {
                const int gm = m0 + wr * 64 + i * 16 + lk * 4 + r;
                const float v = (acc[i][j][r] + bb) * escale;
                const int b_ = gm >> 11, s_ = gm & (S_ - 1);
                Out[(((size_t)(b_ * H_ + h_)) * S_ + s_) * HD_ + hd_] = f2b(v);
            }
        }
    }
}

// ---------------------------------------------------------------------------
// 2. V [B,H,S,HD] -> VT [B,H,HD,S]
// ---------------------------------------------------------------------------
__global__ __launch_bounds__(256)
void transpose_v(const ushort* __restrict__ V, ushort* __restrict__ VT)
{
    __shared__ ushort L[64][72];
    const int t = threadIdx.x;
    const int s0 = blockIdx.x * 64;
    const size_t base = ((size_t)(blockIdx.z * H_ + blockIdx.y)) * S_ * HD_;
    const int r = t >> 2, cb = (t & 3) * 16;

    *(s16x8*)&L[r][cb]     = *(const s16x8*)(V + base + (size_t)(s0 + r) * 64 + cb);
    *(s16x8*)&L[r][cb + 8] = *(const s16x8*)(V + base + (size_t)(s0 + r) * 64 + cb + 8);
    __syncthreads();

    s16x8 o0, o1;
    #pragma unroll
    for (int k = 0; k < 8; ++k) o0[k] = (short)L[cb + k][r];
    #pragma unroll
    for (int k = 0; k < 8; ++k) o1[k] = (short)L[cb + 8 + k][r];
    *(s16x8*)(VT + base + (size_t)r * S_ + s0 + cb)     = o0;
    *(s16x8*)(VT + base + (size_t)r * S_ + s0 + cb + 8) = o1;
}

// ---------------------------------------------------------------------------
// 3. Flash attention bf16, swapped QK^T.
//    Block = (q-tile 64, h, b), 4 waves, wave owns 16 q-rows.
//    QK^T = MFMA(K-frag, Q-frag) -> D[key][q]: lane owns q = l&15, holds
//    16 keys (nt*16 + 4*lk + r).  Row reduce = in-reg + shfl_xor(16,32).
//    P pairs -> LDS b64 writes -> PV = MFMA(P-frag, VT-frag) (round-4 path).
// ---------------------------------------------------------------------------
__global__ __launch_bounds__(256)
void attn_bf16(const ushort* __restrict__ Q, const ushort* __restrict__ K,
               const ushort* __restrict__ VT, const int* __restrict__ mask,
               ushort* __restrict__ ctx)
{
    __shared__ __align__(16) ushort Ks[64 * 64];     // [key][hd]  swizzled
    __shared__ __align__(16) ushort Vs[64 * 64];     // [hd][key]  swizzled
    __shared__ __align__(16) ushort Ps[4][16 * 64];  // per-wave [q][key] swizzled

    const int t = threadIdx.x;
    const int lane = t & 63, w = t >> 6;
    const int lrow = lane & 15, lk = lane >> 4;
    const int q0 = blockIdx.x * 64, h = blockIdx.y, b = blockIdx.z;

    const ushort* Qh = Q + ((size_t)(b * H_ + h)) * S_ * HD_;
    const ushort* Kh = K + ((size_t)(b * H_ + h)) * S_ * HD_;
    const ushort* Vh = VT + ((size_t)(b * H_ + h)) * HD_ * S_;
    const int* mrow = mask + b * S_;

    s16x8 qf[2];
    qf[0] = *(const s16x8*)(Qh + (q0 + w * 16 + lrow) * 64 + lk * 8);
    qf[1] = *(const s16x8*)(Qh + (q0 + w * 16 + lrow) * 64 + 32 + lk * 8);

    f32x4 O[4];
    #pragma unroll
    for (int nt = 0; nt < 4; ++nt) O[nt] = (f32x4)0.f;
    float m_run = -INFINITY;     // per-lane: lane owns q-row (w*16 + lrow)
    float l_run = 0.f;

    const int srow = t >> 3, sslot = t & 7;          // staging coords (2 chunks)

    for (int k0 = 0; k0 < S_; k0 += 64) {
        __syncthreads();
        #pragma unroll
        for (int p = 0; p < 2; ++p) {
            const int row = srow + p * 32;
            const s16x8 kv = *(const s16x8*)(Kh + (size_t)(k0 + row) * 64 + sslot * 8);
            *(s16x8*)(Ks + row * 64 + ((sslot ^ (row & 7)) * 8)) = kv;
            const s16x8 vv = *(const s16x8*)(Vh + (size_t)row * S_ + k0 + sslot * 8);
            *(s16x8*)(Vs + row * 64 + ((sslot ^ (row & 7)) * 8)) = vv;
        }
        __syncthreads();

        // swapped QK^T: sc[nt] = D[key][q], key = nt*16 + 4*lk + r, q = w*16+lrow
        f32x4 sc[4];
        #pragma unroll
        for (int nt = 0; nt < 4; ++nt) sc[nt] = (f32x4)0.f;
        #pragma unroll
        for (int kk = 0; kk < 2; ++kk)
            #pragma unroll
            for (int nt = 0; nt < 4; ++nt) {
                const int krow = nt * 16 + lrow;
                const s16x8 kf = *(const s16x8*)(Ks + krow * 64 + (((kk * 4 + lk) ^ (krow & 7)) * 8));
                sc[nt] = MFMA16(kf, qf[kk], sc[nt]);
            }

        // key masking: lane's keys are k0 + nt*16 + lk*4 + {0..3}
        float s4[4][4];
        #pragma unroll
        for (int nt = 0; nt < 4; ++nt) {
            const int4 km = *(const int4*)(mrow + k0 + nt * 16 + lk * 4);
            s4[nt][0] = km.x ? sc[nt][0] : BIG_NEG_;
            s4[nt][1] = km.y ? sc[nt][1] : BIG_NEG_;
            s4[nt][2] = km.z ? sc[nt][2] : BIG_NEG_;
            s4[nt][3] = km.w ? sc[nt][3] : BIG_NEG_;
        }

        // row max: 15 in-reg + 2 shfl (xor 16, 32)
        float tm = s4[0][0];
        #pragma unroll
        for (int nt = 0; nt < 4; ++nt)
            #pragma unroll
            for (int r = 0; r < 4; ++r) tm = fmaxf(tm, s4[nt][r]);
        tm = fmaxf(tm, __shfl_xor(tm, 16));
        tm = fmaxf(tm, __shfl_xor(tm, 32));

        // T13 defer-max
        if (!__all(tm - m_run <= DEFER_THR_)) {
            const float mn = fmaxf(m_run, tm);
            const float corr = exp2f(m_run - mn);    // 0 on first tile
            m_run = mn;
            l_run *= corr;
            // O rows are q_local = 4*lk + r -> fetch that q's corr
            float cq[4];
            #pragma unroll
            for (int r = 0; r < 4; ++r) cq[r] = __shfl(corr, lk * 4 + r);
            #pragma unroll
            for (int nt = 0; nt < 4; ++nt)
                #pragma unroll
                for (int r = 0; r < 4; ++r) O[nt][r] *= cq[r];
        }

        // P = exp2(s - m), row sum: in-reg + 2 shfl
        float p[4][4];
        float rs = 0.f;
        #pragma unroll
        for (int nt = 0; nt < 4; ++nt)
            #pragma unroll
            for (int r = 0; r < 4; ++r) { p[nt][r] = exp2f(s4[nt][r] - m_run); rs += p[nt][r]; }
        rs += __shfl_xor(rs, 16);
        rs += __shfl_xor(rs, 32);
        l_run += rs;

        // P -> LDS: lane writes its 16 values as 4 x b64 (key-contiguous quads)
        // row q = lrow, keys nt*16 + 4*lk + {0..3}; slot = (nt*2 + (lk>>1)) ^ (lrow&7)
        #pragma unroll
        for (int nt = 0; nt < 4; ++nt) {
            uint2 w2;
            w2.x = ((uint)f2b(p[nt][1]) << 16) | f2b(p[nt][0]);
            w2.y = ((uint)f2b(p[nt][3]) << 16) | f2b(p[nt][2]);
            const int slot = (nt * 2 + (lk >> 1)) ^ (lrow & 7);
            *(uint2*)(&Ps[w][lrow * 64 + slot * 8 + 4 * (lk & 1)]) = w2;
        }

        // PV: O[q][hd] += P[q][key] * VT[hd][key]  (round-4 validated path)
        #pragma unroll
        for (int kk = 0; kk < 2; ++kk) {
            const s16x8 pa = *(const s16x8*)(&Ps[w][lrow * 64 + (((kk * 4 + lk) ^ (lrow & 7)) * 8)]);
            #pragma unroll
            for (int nt = 0; nt < 4; ++nt) {
                const int vrow = nt * 16 + lrow;
                const s16x8 vf = *(const s16x8*)(Vs + vrow * 64 + (((kk * 4 + lk) ^ (vrow & 7)) * 8));
                O[nt] = MFMA16(pa, vf, O[nt]);
            }
        }
    }

    // epilogue: O rows q_local = 4*lk + r; l_run lives at lane q_local
    const float inv = 1.f / l_run;
    float invq[4];
    #pragma unroll
    for (int r = 0; r < 4; ++r) invq[r] = __shfl(inv, lk * 4 + r);
    #pragma unroll
    for (int r = 0; r < 4; ++r) {
        const int s = q0 + w * 16 + lk * 4 + r;
        #pragma unroll
        for (int nt = 0; nt < 4; ++nt)
            ctx[((size_t)(b * S_ + s)) * D_ + h * 64 + nt * 16 + lrow] = f2b(O[nt][r] * invq[r]);
    }
}

// ---------------------------------------------------------------------------
// 4. out GEMM: ctx(bf16) @ Wo^T + bo, row-mask, f32 out.
// ---------------------------------------------------------------------------
__global__ __launch_bounds__(256)
void out_gemm(const ushort* __restrict__ Xb, const ushort* __restrict__ Wb,
              const float* __restrict__ bias, const int* __restrict__ mask,
              float* __restrict__ Cf)
{
    __shared__ ushort As[128 * 64];
    __shared__ ushort Bs[128 * 64];

    const int t = threadIdx.x;
    const int lane = t & 63;
    const int w = t >> 6, wr = w >> 1, wc = w & 1;
    const int lrow = lane & 15, lk = lane >> 4;
    const int m0 = blockIdx.x * 128, n0 = blockIdx.y * 128;

    f32x4 acc[4][4];
    #pragma unroll
    for (int i = 0; i < 4; ++i)
        #pragma unroll
        for (int j = 0; j < 4; ++j) acc[i][j] = (f32x4)0.f;

    for (int k0 = 0; k0 < D_; k0 += 64) {
        __syncthreads();
        #pragma unroll
        for (int p = 0; p < 4; ++p) {
            const int c = p * 256 + t;
            const int row = c >> 3, slot = c & 7;
            gload16(Xb + (size_t)(m0 + row) * 1024 + k0 + slot * 8,
                    As + (size_t)(p * 256 + (t & 192)) * 8);
            gload16(Wb + (size_t)(n0 + row) * 1024 + k0 + slot * 8,
                    Bs + (size_t)(p * 256 + (t & 192)) * 8);
        }
        __syncthreads();

        #pragma unroll
        for (int kk = 0; kk < 2; ++kk) {
            s16x8 af[4], bf[4];
            #pragma unroll
            for (int i = 0; i < 4; ++i)
                af[i] = *(const s16x8*)(As + (wr * 64 + i * 16 + lrow) * 64 + kk * 32 + lk * 8);
            #pragma unroll
            for (int j = 0; j < 4; ++j)
                bf[j] = *(const s16x8*)(Bs + (wc * 64 + j * 16 + lrow) * 64 + kk * 32 + lk * 8);
            #pragma unroll
            for (int i = 0; i < 4; ++i)
                #pragma unroll
                for (int j = 0; j < 4; ++j)
                    acc[i][j] = MFMA16(af[i], bf[j], acc[i][j]);
        }
    }

    #pragma unroll
    for (int i = 0; i < 4; ++i) {
        #pragma unroll
        for (int j = 0; j < 4; ++j) {
            const int gn = n0 + wc * 64 + j * 16 + lrow;
            const float bb = bias[gn];
            #pragma unroll
            for (int r = 0; r < 4; ++r) {
                const int gm = m0 + wr * 64 + i * 16 + lk * 4 + r;
                const float v = (acc[i][j][r] + bb) * (float)mask[gm];
                Cf[(size_t)gm * 1024 + gn] = v;
            }
        }
    }
}

extern "C" void kernel_launch(void* const* d_in, const int* in_sizes, int n_in,
                              void* d_out, int out_size, void* d_ws, size_t ws_size,
                              hipStream_t stream) {
    const float* hidden = (const float*)d_in[0];
    const int*   mask   = (const int*)d_in[1];
    const float* Wq = (const float*)d_in[2];
    const float* bq = (const float*)d_in[3];
    const float* Wk = (const float*)d_in[4];
    const float* bk = (const float*)d_in[5];
    const float* Wv = (const float*)d_in[6];
    const float* bv = (const float*)d_in[7];
    const float* Wo = (const float*)d_in[8];
    const float* bo = (const float*)d_in[9];
    float* out = (float*)d_out;

    ushort* ws = (ushort*)d_ws;
    const size_t T = (size_t)B_ * H_ * S_ * HD_;   // 8388608 elems
    ushort* Xb  = ws;                               // [8192][1024] bf16
    ushort* Wb  = ws + T;                           // 4 x [1024][1024] bf16
    ushort* Qb  = ws + T + 4194304;
    ushort* Kb  = Qb + T;
    ushort* Vb  = Kb + T;
    ushort* VTb = Vb + T;
    ushort* Cb  = VTb + T;                          // ctx bf16 [B,S,D]

    const dim3 bb(256);
    convert_all<<<2048, bb, 0, stream>>>(hidden, mask, Wq, Wk, Wv, Wo, Xb, Wb);
    qkv_gemm<<<dim3(64, 24), bb, 0, stream>>>(Xb, Wb, bq, bk, bv, Qb, Kb, Vb);
    transpose_v<<<dim3(S_ / 64, H_, B_), bb, 0, stream>>>(Vb, VTb);
    attn_bf16<<<dim3(S_ / 64, H_, B_), bb, 0, stream>>>(Qb, Kb, VTb, mask, Cb);
    out_gemm<<<dim3(64, 8), bb, 0, stream>>>(Cb, Wb + 3 * 1048576, bo, mask, out);
}

// Round 11
// 373.894 us; speedup vs baseline: 5.1119x; 1.0342x over previous
//
#include <hip/hip_runtime.h>
#include <math.h>

// ---------------------------------------------------------------------------
// Masked MHA, bf16-MFMA pipeline v4.  B=4 S=2048 D=1024 H=16 HD=64
//  0. convert_all: hidden*mask -> Xb bf16; Wq|Wk|Wv|Wo -> Wb bf16
//  1. qkv_gemm   : fused 3-in-1 GEMM (global_load_lds w16), Q pre-scaled by
//                  SCALE*log2(e)  -> Q/K/V bf16 [B,H,S,HD]
//  2. transpose_v: V -> VT [B,H,HD,S]
//  3. attn_bf16  : flash, swapped QK^T, exp2 softmax, defer-max THR=8,
//                  K/V staged via global_load_lds w16 (pre-swizzled source),
//                  P packed via v_cvt_pk_bf16_f32 -> ctx bf16 [B,S,D]
//  4. out_gemm   : ctx @ Wo^T + bo, query-mask -> f32 out
// MFMA 16x16x32_bf16 layouts (verified rounds 4-10):
//   A: row=l&15, k=(l>>4)*8+j ; B: col=l&15, k=(l>>4)*8+j ;
//   C/D: col=l&15, row=(l>>4)*4+reg
// ---------------------------------------------------------------------------

typedef __attribute__((ext_vector_type(4))) float f32x4;
typedef __attribute__((ext_vector_type(8))) short s16x8;

#define MFMA16(a, b, c) __builtin_amdgcn_mfma_f32_16x16x32_bf16((a), (b), (c), 0, 0, 0)

constexpr int B_ = 4, S_ = 2048, D_ = 1024, H_ = 16, HD_ = 64;
constexpr float SCALE_ = 0.125f;
constexpr float LOG2E_ = 1.4426950408889634f;
constexpr float BIG_NEG_ = -1e9f;      // log2-domain "minus infinity"
constexpr float DEFER_THR_ = 8.f;      // T13: P bounded by 2^8

__device__ __forceinline__ ushort f2b(float x) {   // f32 -> bf16 bits, RNE
    unsigned u = __float_as_uint(x);
    return (ushort)((u + 0x7FFFu + ((u >> 16) & 1u)) >> 16);
}

__device__ __forceinline__ void gload16(const ushort* g, ushort* l) {
    __builtin_amdgcn_global_load_lds(
        (const __attribute__((address_space(1))) void*)g,
        (__attribute__((address_space(3))) void*)l, 16, 0, 0);
}

// ---------------------------------------------------------------------------
// 0. convert: X (masked) and 4 weight matrices -> bf16
// ---------------------------------------------------------------------------
__global__ __launch_bounds__(256)
void convert_all(const float* __restrict__ hidden, const int* __restrict__ mask,
                 const float* __restrict__ Wq, const float* __restrict__ Wk,
                 const float* __restrict__ Wv, const float* __restrict__ Wo,
                 ushort* __restrict__ Xb, ushort* __restrict__ Wb)
{
    const int NXC = 1048576;                  // 8.4M X elems / 8
    const int NWC = 131072;                   // 1M W elems / 8
    const int TOT = NXC + 4 * NWC;
    for (int idx = blockIdx.x * 256 + threadIdx.x; idx < TOT; idx += gridDim.x * 256) {
        if (idx < NXC) {
            const size_t e = (size_t)idx * 8;
            const float mf = (float)mask[e >> 10];
            const float4 a = *(const float4*)(hidden + e);
            const float4 b = *(const float4*)(hidden + e + 4);
            s16x8 v;
            v[0] = (short)f2b(a.x * mf); v[1] = (short)f2b(a.y * mf);
            v[2] = (short)f2b(a.z * mf); v[3] = (short)f2b(a.w * mf);
            v[4] = (short)f2b(b.x * mf); v[5] = (short)f2b(b.y * mf);
            v[6] = (short)f2b(b.z * mf); v[7] = (short)f2b(b.w * mf);
            *(s16x8*)(Xb + e) = v;
        } else {
            const int c = idx - NXC;
            const int sel = c >> 17;
            const size_t off = (size_t)(c & (NWC - 1)) * 8;
            const float* src = (sel == 0) ? Wq : (sel == 1) ? Wk : (sel == 2) ? Wv : Wo;
            const float4 a = *(const float4*)(src + off);
            const float4 b = *(const float4*)(src + off + 4);
            s16x8 v;
            v[0] = (short)f2b(a.x); v[1] = (short)f2b(a.y);
            v[2] = (short)f2b(a.z); v[3] = (short)f2b(a.w);
            v[4] = (short)f2b(b.x); v[5] = (short)f2b(b.y);
            v[6] = (short)f2b(b.z); v[7] = (short)f2b(b.w);
            *(s16x8*)(Wb + (size_t)sel * 1048576 + off) = v;
        }
    }
}

// ---------------------------------------------------------------------------
// 1. fused QKV GEMM, 128x128 tile, BK=64, global_load_lds w16.
// ---------------------------------------------------------------------------
__global__ __launch_bounds__(256)
void qkv_gemm(const ushort* __restrict__ Xb, const ushort* __restrict__ Wall,
              const float* __restrict__ bq, const float* __restrict__ bk,
              const float* __restrict__ bv,
              ushort* __restrict__ Qb, ushort* __restrict__ Kb,
              ushort* __restrict__ Vb)
{
    __shared__ ushort As[128 * 64];
    __shared__ ushort Bs[128 * 64];

    const int t = threadIdx.x;
    const int lane = t & 63;
    const int w = t >> 6, wr = w >> 1, wc = w & 1;
    const int lrow = lane & 15, lk = lane >> 4;
    const int m0 = blockIdx.x * 128;
    const int sel = blockIdx.y >> 3;
    const int n0 = (blockIdx.y & 7) * 128;

    const ushort* Wb = Wall + (size_t)sel * 1048576;
    const float* bias = (sel == 0) ? bq : (sel == 1) ? bk : bv;
    ushort* Out = (sel == 0) ? Qb : (sel == 1) ? Kb : Vb;
    const float escale = (sel == 0) ? SCALE_ * LOG2E_ : 1.f;

    f32x4 acc[4][4];
    #pragma unroll
    for (int i = 0; i < 4; ++i)
        #pragma unroll
        for (int j = 0; j < 4; ++j) acc[i][j] = (f32x4)0.f;

    for (int k0 = 0; k0 < D_; k0 += 64) {
        __syncthreads();
        #pragma unroll
        for (int p = 0; p < 4; ++p) {
            const int c = p * 256 + t;
            const int row = c >> 3, slot = c & 7;
            gload16(Xb + (size_t)(m0 + row) * 1024 + k0 + slot * 8,
                    As + (size_t)(p * 256 + (t & 192)) * 8);
            gload16(Wb + (size_t)(n0 + row) * 1024 + k0 + slot * 8,
                    Bs + (size_t)(p * 256 + (t & 192)) * 8);
        }
        __syncthreads();

        #pragma unroll
        for (int kk = 0; kk < 2; ++kk) {
            s16x8 af[4], bf[4];
            #pragma unroll
            for (int i = 0; i < 4; ++i)
                af[i] = *(const s16x8*)(As + (wr * 64 + i * 16 + lrow) * 64 + kk * 32 + lk * 8);
            #pragma unroll
            for (int j = 0; j < 4; ++j)
                bf[j] = *(const s16x8*)(Bs + (wc * 64 + j * 16 + lrow) * 64 + kk * 32 + lk * 8);
            #pragma unroll
            for (int i = 0; i < 4; ++i)
                #pragma unroll
                for (int j = 0; j < 4; ++j)
                    acc[i][j] = MFMA16(af[i], bf[j], acc[i][j]);
        }
    }

    #pragma unroll
    for (int i = 0; i < 4; ++i) {
        #pragma unroll
        for (int j = 0; j < 4; ++j) {
            const int gn = n0 + wc * 64 + j * 16 + lrow;
            const float bb = bias[gn];
            const int h_ = gn >> 6, hd_ = gn & 63;
            #pragma unroll
            for (int r = 0; r < 4; ++r) {
                const int gm = m0 + wr * 64 + i * 16 + lk * 4 + r;
                const float v = (acc[i][j][r] + bb) * escale;
                const int b_ = gm >> 11, s_ = gm & (S_ - 1);
                Out[(((size_t)(b_ * H_ + h_)) * S_ + s_) * HD_ + hd_] = f2b(v);
            }
        }
    }
}

// ---------------------------------------------------------------------------
// 2. V [B,H,S,HD] -> VT [B,H,HD,S]
// ---------------------------------------------------------------------------
__global__ __launch_bounds__(256)
void transpose_v(const ushort* __restrict__ V, ushort* __restrict__ VT)
{
    __shared__ ushort L[64][72];
    const int t = threadIdx.x;
    const int s0 = blockIdx.x * 64;
    const size_t base = ((size_t)(blockIdx.z * H_ + blockIdx.y)) * S_ * HD_;
    const int r = t >> 2, cb = (t & 3) * 16;

    *(s16x8*)&L[r][cb]     = *(const s16x8*)(V + base + (size_t)(s0 + r) * 64 + cb);
    *(s16x8*)&L[r][cb + 8] = *(const s16x8*)(V + base + (size_t)(s0 + r) * 64 + cb + 8);
    __syncthreads();

    s16x8 o0, o1;
    #pragma unroll
    for (int k = 0; k < 8; ++k) o0[k] = (short)L[cb + k][r];
    #pragma unroll
    for (int k = 0; k < 8; ++k) o1[k] = (short)L[cb + 8 + k][r];
    *(s16x8*)(VT + base + (size_t)r * S_ + s0 + cb)     = o0;
    *(s16x8*)(VT + base + (size_t)r * S_ + s0 + cb + 8) = o1;
}

// ---------------------------------------------------------------------------
// 3. Flash attention bf16, swapped QK^T.
//    K/V staging: global_load_lds w16 with PRE-SWIZZLED global source
//    (rule #21: linear LDS dest + inverse-swizzled source + swizzled read
//    = byte-identical LDS contents to the round-10 reg-staged version).
//    P pack: v_cvt_pk_bf16_f32 (T12) replaces 16 manual f2b.
// ---------------------------------------------------------------------------
__global__ __launch_bounds__(256)
void attn_bf16(const ushort* __restrict__ Q, const ushort* __restrict__ K,
               const ushort* __restrict__ VT, const int* __restrict__ mask,
               ushort* __restrict__ ctx)
{
    __shared__ __align__(16) ushort Ks[64 * 64];     // [key][hd]  swizzled
    __shared__ __align__(16) ushort Vs[64 * 64];     // [hd][key]  swizzled
    __shared__ __align__(16) ushort Ps[4][16 * 64];  // per-wave [q][key] swizzled

    const int t = threadIdx.x;
    const int lane = t & 63, w = t >> 6;
    const int lrow = lane & 15, lk = lane >> 4;
    const int q0 = blockIdx.x * 64, h = blockIdx.y, b = blockIdx.z;

    const ushort* Qh = Q + ((size_t)(b * H_ + h)) * S_ * HD_;
    const ushort* Kh = K + ((size_t)(b * H_ + h)) * S_ * HD_;
    const ushort* Vh = VT + ((size_t)(b * H_ + h)) * HD_ * S_;
    const int* mrow = mask + b * S_;

    s16x8 qf[2];
    qf[0] = *(const s16x8*)(Qh + (q0 + w * 16 + lrow) * 64 + lk * 8);
    qf[1] = *(const s16x8*)(Qh + (q0 + w * 16 + lrow) * 64 + 32 + lk * 8);

    f32x4 O[4];
    #pragma unroll
    for (int nt = 0; nt < 4; ++nt) O[nt] = (f32x4)0.f;
    float m_run = -INFINITY;     // per-lane: lane owns q-row (w*16 + lrow)
    float l_run = 0.f;

    // staging coords: chunk p covers rows p*32 + (t>>3), slot t&7.
    // Linear LDS chunk index = p*256 + t; lane's global slot pre-swizzled.
    const int srow = t >> 3, sslot = t & 7;

    for (int k0 = 0; k0 < S_; k0 += 64) {
        __syncthreads();
        #pragma unroll
        for (int p = 0; p < 2; ++p) {
            const int row = srow + p * 32;
            const int gs = (sslot ^ (row & 7)) * 8;     // pre-swizzled source
            gload16(Kh + (size_t)(k0 + row) * 64 + gs,
                    Ks + (size_t)(p * 256 + (t & 192)) * 8);
            gload16(Vh + (size_t)row * S_ + k0 + gs,
                    Vs + (size_t)(p * 256 + (t & 192)) * 8);
        }
        __syncthreads();

        // swapped QK^T: sc[nt] = D[key][q], key = nt*16 + 4*lk + r, q = w*16+lrow
        f32x4 sc[4];
        #pragma unroll
        for (int nt = 0; nt < 4; ++nt) sc[nt] = (f32x4)0.f;
        #pragma unroll
        for (int kk = 0; kk < 2; ++kk)
            #pragma unroll
            for (int nt = 0; nt < 4; ++nt) {
                const int krow = nt * 16 + lrow;
                const s16x8 kf = *(const s16x8*)(Ks + krow * 64 + (((kk * 4 + lk) ^ (krow & 7)) * 8));
                sc[nt] = MFMA16(kf, qf[kk], sc[nt]);
            }

        // key masking: lane's keys are k0 + nt*16 + lk*4 + {0..3}
        float s4[4][4];
        #pragma unroll
        for (int nt = 0; nt < 4; ++nt) {
            const int4 km = *(const int4*)(mrow + k0 + nt * 16 + lk * 4);
            s4[nt][0] = km.x ? sc[nt][0] : BIG_NEG_;
            s4[nt][1] = km.y ? sc[nt][1] : BIG_NEG_;
            s4[nt][2] = km.z ? sc[nt][2] : BIG_NEG_;
            s4[nt][3] = km.w ? sc[nt][3] : BIG_NEG_;
        }

        // row max: 15 in-reg + 2 shfl (xor 16, 32)
        float tm = s4[0][0];
        #pragma unroll
        for (int nt = 0; nt < 4; ++nt)
            #pragma unroll
            for (int r = 0; r < 4; ++r) tm = fmaxf(tm, s4[nt][r]);
        tm = fmaxf(tm, __shfl_xor(tm, 16));
        tm = fmaxf(tm, __shfl_xor(tm, 32));

        // T13 defer-max
        if (!__all(tm - m_run <= DEFER_THR_)) {
            const float mn = fmaxf(m_run, tm);
            const float corr = exp2f(m_run - mn);    // 0 on first tile
            m_run = mn;
            l_run *= corr;
            // O rows are q_local = 4*lk + r -> fetch that q's corr
            float cq[4];
            #pragma unroll
            for (int r = 0; r < 4; ++r) cq[r] = __shfl(corr, lk * 4 + r);
            #pragma unroll
            for (int nt = 0; nt < 4; ++nt)
                #pragma unroll
                for (int r = 0; r < 4; ++r) O[nt][r] *= cq[r];
        }

        // P = exp2(s - m), row sum: in-reg + 2 shfl
        float p[4][4];
        float rs = 0.f;
        #pragma unroll
        for (int nt = 0; nt < 4; ++nt)
            #pragma unroll
            for (int r = 0; r < 4; ++r) { p[nt][r] = exp2f(s4[nt][r] - m_run); rs += p[nt][r]; }
        rs += __shfl_xor(rs, 16);
        rs += __shfl_xor(rs, 32);
        l_run += rs;

        // P -> LDS: v_cvt_pk_bf16_f32 packs pairs (T12); 4 x b64 writes
        // row q = lrow, keys nt*16 + 4*lk + {0..3}; slot = (nt*2 + (lk>>1)) ^ (lrow&7)
        #pragma unroll
        for (int nt = 0; nt < 4; ++nt) {
            uint2 w2;
            asm("v_cvt_pk_bf16_f32 %0, %1, %2" : "=v"(w2.x) : "v"(p[nt][0]), "v"(p[nt][1]));
            asm("v_cvt_pk_bf16_f32 %0, %1, %2" : "=v"(w2.y) : "v"(p[nt][2]), "v"(p[nt][3]));
            const int slot = (nt * 2 + (lk >> 1)) ^ (lrow & 7);
            *(uint2*)(&Ps[w][lrow * 64 + slot * 8 + 4 * (lk & 1)]) = w2;
        }

        // PV: O[q][hd] += P[q][key] * VT[hd][key]
        #pragma unroll
        for (int kk = 0; kk < 2; ++kk) {
            const s16x8 pa = *(const s16x8*)(&Ps[w][lrow * 64 + (((kk * 4 + lk) ^ (lrow & 7)) * 8)]);
            #pragma unroll
            for (int nt = 0; nt < 4; ++nt) {
                const int vrow = nt * 16 + lrow;
                const s16x8 vf = *(const s16x8*)(Vs + vrow * 64 + (((kk * 4 + lk) ^ (vrow & 7)) * 8));
                O[nt] = MFMA16(pa, vf, O[nt]);
            }
        }
    }

    // epilogue: O rows q_local = 4*lk + r; l_run lives at lane q_local
    const float inv = 1.f / l_run;
    float invq[4];
    #pragma unroll
    for (int r = 0; r < 4; ++r) invq[r] = __shfl(inv, lk * 4 + r);
    #pragma unroll
    for (int r = 0; r < 4; ++r) {
        const int s = q0 + w * 16 + lk * 4 + r;
        #pragma unroll
        for (int nt = 0; nt < 4; ++nt)
            ctx[((size_t)(b * S_ + s)) * D_ + h * 64 + nt * 16 + lrow] = f2b(O[nt][r] * invq[r]);
    }
}

// ---------------------------------------------------------------------------
// 4. out GEMM: ctx(bf16) @ Wo^T + bo, row-mask, f32 out.
// ---------------------------------------------------------------------------
__global__ __launch_bounds__(256)
void out_gemm(const ushort* __restrict__ Xb, const ushort* __restrict__ Wb,
              const float* __restrict__ bias, const int* __restrict__ mask,
              float* __restrict__ Cf)
{
    __shared__ ushort As[128 * 64];
    __shared__ ushort Bs[128 * 64];

    const int t = threadIdx.x;
    const int lane = t & 63;
    const int w = t >> 6, wr = w >> 1, wc = w & 1;
    const int lrow = lane & 15, lk = lane >> 4;
    const int m0 = blockIdx.x * 128, n0 = blockIdx.y * 128;

    f32x4 acc[4][4];
    #pragma unroll
    for (int i = 0; i < 4; ++i)
        #pragma unroll
        for (int j = 0; j < 4; ++j) acc[i][j] = (f32x4)0.f;

    for (int k0 = 0; k0 < D_; k0 += 64) {
        __syncthreads();
        #pragma unroll
        for (int p = 0; p < 4; ++p) {
            const int c = p * 256 + t;
            const int row = c >> 3, slot = c & 7;
            gload16(Xb + (size_t)(m0 + row) * 1024 + k0 + slot * 8,
                    As + (size_t)(p * 256 + (t & 192)) * 8);
            gload16(Wb + (size_t)(n0 + row) * 1024 + k0 + slot * 8,
                    Bs + (size_t)(p * 256 + (t & 192)) * 8);
        }
        __syncthreads();

        #pragma unroll
        for (int kk = 0; kk < 2; ++kk) {
            s16x8 af[4], bf[4];
            #pragma unroll
            for (int i = 0; i < 4; ++i)
                af[i] = *(const s16x8*)(As + (wr * 64 + i * 16 + lrow) * 64 + kk * 32 + lk * 8);
            #pragma unroll
            for (int j = 0; j < 4; ++j)
                bf[j] = *(const s16x8*)(Bs + (wc * 64 + j * 16 + lrow) * 64 + kk * 32 + lk * 8);
            #pragma unroll
            for (int i = 0; i < 4; ++i)
                #pragma unroll
                for (int j = 0; j < 4; ++j)
                    acc[i][j] = MFMA16(af[i], bf[j], acc[i][j]);
        }
    }

    #pragma unroll
    for (int i = 0; i < 4; ++i) {
        #pragma unroll
        for (int j = 0; j < 4; ++j) {
            const int gn = n0 + wc * 64 + j * 16 + lrow;
            const float bb = bias[gn];
            #pragma unroll
            for (int r = 0; r < 4; ++r) {
                const int gm = m0 + wr * 64 + i * 16 + lk * 4 + r;
                const float v = (acc[i][j][r] + bb) * (float)mask[gm];
                Cf[(size_t)gm * 1024 + gn] = v;
            }
        }
    }
}

extern "C" void kernel_launch(void* const* d_in, const int* in_sizes, int n_in,
                              void* d_out, int out_size, void* d_ws, size_t ws_size,
                              hipStream_t stream) {
    const float* hidden = (const float*)d_in[0];
    const int*   mask   = (const int*)d_in[1];
    const float* Wq = (const float*)d_in[2];
    const float* bq = (const float*)d_in[3];
    const float* Wk = (const float*)d_in[4];
    const float* bk = (const float*)d_in[5];
    const float* Wv = (const float*)d_in[6];
    const float* bv = (const float*)d_in[7];
    const float* Wo = (const float*)d_in[8];
    const float* bo = (const float*)d_in[9];
    float* out = (float*)d_out;

    ushort* ws = (ushort*)d_ws;
    const size_t T = (size_t)B_ * H_ * S_ * HD_;   // 8388608 elems
    ushort* Xb  = ws;                               // [8192][1024] bf16
    ushort* Wb  = ws + T;                           // 4 x [1024][1024] bf16
    ushort* Qb  = ws + T + 4194304;
    ushort* Kb  = Qb + T;
    ushort* Vb  = Kb + T;
    ushort* VTb = Vb + T;
    ushort* Cb  = VTb + T;                          // ctx bf16 [B,S,D]

    const dim3 bb(256);
    convert_all<<<2048, bb, 0, stream>>>(hidden, mask, Wq, Wk, Wv, Wo, Xb, Wb);
    qkv_gemm<<<dim3(64, 24), bb, 0, stream>>>(Xb, Wb, bq, bk, bv, Qb, Kb, Vb);
    transpose_v<<<dim3(S_ / 64, H_, B_), bb, 0, stream>>>(Vb, VTb);
    attn_bf16<<<dim3(S_ / 64, H_, B_), bb, 0, stream>>>(Qb, Kb, VTb, mask, Cb);
    out_gemm<<<dim3(64, 8), bb, 0, stream>>>(Cb, Wb + 3 * 1048576, bo, mask, out);
}